// Round 1
// baseline (618.963 us; speedup 1.0000x reference)
//
#include <hip/hip_runtime.h>

typedef __bf16 bf16x8 __attribute__((ext_vector_type(8)));
typedef float f32x4 __attribute__((ext_vector_type(4)));

#define HW 16384
#define QKV_C 1152

union U4B8 { uint4 u; bf16x8 v; __bf16 h[8]; };
union U2B4 { uint2 u; __bf16 h[4]; };

// ---------------------------------------------------------------------------
// K1: qkv[b][hw][o] (bf16, token-major) = w_qkv[o][c] * x[b][c][hw] + b_qkv[o]
// grid (128 hw-tiles, 9 o-tiles, 4 b), 256 threads (4 waves, 2x2 wave grid)
// MFMA 16x16x32 bf16; A = w_qkv (m=o), B = x (n=hw, LDS-transposed staging)
// ---------------------------------------------------------------------------
__global__ __launch_bounds__(256) void k_qkv(const float* __restrict__ x,
    const float* __restrict__ wq, const float* __restrict__ bq,
    __bf16* __restrict__ qkv)
{
    __shared__ __bf16 As[128 * 72];  // w_qkv tile [o][c], pad 72
    __shared__ __bf16 Bs[128 * 72];  // x tile [hw][c] (transposed on store)
    const int tid = threadIdx.x;
    const int hw0 = blockIdx.x * 128;
    const int o0  = blockIdx.y * 128;
    const int b   = blockIdx.z;
    const float* xb = x + (size_t)b * 384 * HW;

    f32x4 acc[4][4];
#pragma unroll
    for (int i = 0; i < 4; ++i)
#pragma unroll
        for (int j = 0; j < 4; ++j)
#pragma unroll
            for (int e = 0; e < 4; ++e) acc[i][j][e] = 0.0f;

    const int l = tid & 63;
    const int wv = tid >> 6;
    const int wm = wv & 1;    // o 64-half
    const int wn = wv >> 1;   // hw 64-half
    const int l16 = l & 15, quad = l >> 4;

    for (int kt = 0; kt < 6; ++kt) {
        const int c0 = kt * 64;
        // stage w_qkv tile: 128 o x 64 c (fp32 -> bf16)
#pragma unroll
        for (int it = 0; it < 8; ++it) {
            int unit = it * 256 + tid;
            int o = unit >> 4, ch = unit & 15;
            float4 f = *(const float4*)(wq + (size_t)(o0 + o) * 384 + c0 + ch * 4);
            U2B4 t;
            t.h[0] = (__bf16)f.x; t.h[1] = (__bf16)f.y;
            t.h[2] = (__bf16)f.z; t.h[3] = (__bf16)f.w;
            *(uint2*)(As + o * 72 + ch * 4) = t.u;
        }
        // stage x tile transposed: global [c][hw] -> LDS [hw][c]
        {
            int hw4 = tid & 31;
            int cb  = tid >> 5;
#pragma unroll
            for (int it = 0; it < 8; ++it) {
                int c = it * 8 + cb;
                float4 f = *(const float4*)(xb + (size_t)(c0 + c) * HW + hw0 + hw4 * 4);
                Bs[(hw4 * 4 + 0) * 72 + c] = (__bf16)f.x;
                Bs[(hw4 * 4 + 1) * 72 + c] = (__bf16)f.y;
                Bs[(hw4 * 4 + 2) * 72 + c] = (__bf16)f.z;
                Bs[(hw4 * 4 + 3) * 72 + c] = (__bf16)f.w;
            }
        }
        __syncthreads();
#pragma unroll
        for (int ks = 0; ks < 2; ++ks) {
            bf16x8 a[4], bb[4];
#pragma unroll
            for (int t = 0; t < 4; ++t)
                a[t] = *(const bf16x8*)(As + (wm * 64 + t * 16 + l16) * 72 + ks * 32 + quad * 8);
#pragma unroll
            for (int t = 0; t < 4; ++t)
                bb[t] = *(const bf16x8*)(Bs + (wn * 64 + t * 16 + l16) * 72 + ks * 32 + quad * 8);
#pragma unroll
            for (int mt = 0; mt < 4; ++mt)
#pragma unroll
                for (int nt = 0; nt < 4; ++nt)
                    acc[mt][nt] = __builtin_amdgcn_mfma_f32_16x16x32_bf16(
                        a[mt], bb[nt], acc[mt][nt], 0, 0, 0);
        }
        __syncthreads();
    }

    // epilogue: D[m=o][n=hw]; C-layout col=l16 -> hw, row=quad*4+e -> o
    __bf16* qb = qkv + (size_t)b * HW * QKV_C;
#pragma unroll
    for (int mt = 0; mt < 4; ++mt) {
        int oo = o0 + wm * 64 + mt * 16 + quad * 4;
        float4 bias = *(const float4*)(bq + oo);
#pragma unroll
        for (int nt = 0; nt < 4; ++nt) {
            int hw = hw0 + wn * 64 + nt * 16 + l16;
            U2B4 t;
            t.h[0] = (__bf16)(acc[mt][nt][0] + bias.x);
            t.h[1] = (__bf16)(acc[mt][nt][1] + bias.y);
            t.h[2] = (__bf16)(acc[mt][nt][2] + bias.z);
            t.h[3] = (__bf16)(acc[mt][nt][3] + bias.w);
            *(uint2*)(qb + (size_t)hw * QKV_C + oo) = t.u;
        }
    }
}

// ---------------------------------------------------------------------------
// K2: windowed MHA. One wave per (window, head, branch). 192 thr = 3 waves.
// wid < 6144: aligned branch -> y1 ; else shifted (pad 4) -> y2.
// Zero-padded tokens: q=k=v=0 (logit 0 participates in softmax, as reference).
// ---------------------------------------------------------------------------
__global__ __launch_bounds__(192) void k_attn(const __bf16* __restrict__ qkv,
    __bf16* __restrict__ y1, __bf16* __restrict__ y2)
{
    __shared__ __bf16 sm[3][2][64 * 72];
    const int tid = threadIdx.x;
    const int l = tid & 63, wv = tid >> 6;
    const int wid = blockIdx.x * 3 + wv;
    const bool shifted = wid >= 6144;
    const int w2 = shifted ? wid - 6144 : wid;
    const int head = w2 % 6;
    const int win = w2 / 6;
    const int nw = shifted ? 17 : 16;
    const int wx = win % nw;
    const int t2 = win / nw;
    const int wy = t2 % nw;
    const int b  = t2 / nw;
    const int h0 = wy * 8 - (shifted ? 4 : 0);
    const int w0 = wx * 8 - (shifted ? 4 : 0);
    const __bf16* qb = qkv + (size_t)b * HW * QKV_C;
    __bf16* VT = &sm[wv][0][0];  // V^T [c][tok], later reused as O [tok][c]
    __bf16* P  = &sm[wv][1][0];  // P  [tok][j]
    const int l16 = l & 15, quad = l >> 4;
    const int cbase = head * 64;

    // stage V^T
#pragma unroll
    for (int it = 0; it < 8; ++it) {
        int unit = it * 64 + l;
        int tok = unit >> 3, c8 = unit & 7;
        int hh = h0 + (tok >> 3), ww = w0 + (tok & 7);
        U4B8 t;
        if ((unsigned)hh < 128u && (unsigned)ww < 128u)
            t.u = *(const uint4*)(qb + (size_t)(hh * 128 + ww) * QKV_C + 768 + cbase + c8 * 8);
        else
            t.u = make_uint4(0, 0, 0, 0);
#pragma unroll
        for (int e = 0; e < 8; ++e) VT[(c8 * 8 + e) * 72 + tok] = t.h[e];
    }

    // per-16-token-tile offsets for this lane
    size_t toff[4]; bool tval[4];
#pragma unroll
    for (int t = 0; t < 4; ++t) {
        int tok = t * 16 + l16;
        int hh = h0 + (tok >> 3), ww = w0 + (tok & 7);
        tval[t] = ((unsigned)hh < 128u && (unsigned)ww < 128u);
        toff[t] = tval[t] ? (size_t)(hh * 128 + ww) * QKV_C : 0;
    }

    // S = Q K^T  (Q,K fragments direct from global; token-major layout matches)
    f32x4 s[4][4];
#pragma unroll
    for (int i = 0; i < 4; ++i)
#pragma unroll
        for (int j = 0; j < 4; ++j)
#pragma unroll
            for (int e = 0; e < 4; ++e) s[i][j][e] = 0.0f;

#pragma unroll
    for (int ks = 0; ks < 2; ++ks) {
        bf16x8 aq[4], bk[4];
#pragma unroll
        for (int t = 0; t < 4; ++t) {
            U4B8 uq, uk;
            if (tval[t]) {
                uq.u = *(const uint4*)(qb + toff[t] + cbase + ks * 32 + quad * 8);
                uk.u = *(const uint4*)(qb + toff[t] + 384 + cbase + ks * 32 + quad * 8);
            } else {
                uq.u = make_uint4(0, 0, 0, 0);
                uk.u = make_uint4(0, 0, 0, 0);
            }
            aq[t] = uq.v;
            bk[t] = uk.v;
        }
#pragma unroll
        for (int mt = 0; mt < 4; ++mt)
#pragma unroll
            for (int nt = 0; nt < 4; ++nt)
                s[mt][nt] = __builtin_amdgcn_mfma_f32_16x16x32_bf16(
                    aq[mt], bk[nt], s[mt][nt], 0, 0, 0);
    }

    // softmax (scale 1/8); row = mt*16 + quad*4 + e, cols across l16 x nt
#pragma unroll
    for (int mt = 0; mt < 4; ++mt) {
#pragma unroll
        for (int e = 0; e < 4; ++e) {
            float m_ = fmaxf(fmaxf(s[mt][0][e], s[mt][1][e]),
                             fmaxf(s[mt][2][e], s[mt][3][e]));
#pragma unroll
            for (int st = 1; st < 16; st <<= 1) m_ = fmaxf(m_, __shfl_xor(m_, st, 64));
            float p[4];
#pragma unroll
            for (int nt = 0; nt < 4; ++nt) p[nt] = __expf((s[mt][nt][e] - m_) * 0.125f);
            float sum = p[0] + p[1] + p[2] + p[3];
#pragma unroll
            for (int st = 1; st < 16; st <<= 1) sum += __shfl_xor(sum, st, 64);
            float r = __fdividef(1.0f, sum);
            int row = mt * 16 + quad * 4 + e;
#pragma unroll
            for (int nt = 0; nt < 4; ++nt)
                P[row * 72 + nt * 16 + l16] = (__bf16)(p[nt] * r);
        }
    }
    __syncthreads();

    // O = P V
    f32x4 o[4][4];
#pragma unroll
    for (int i = 0; i < 4; ++i)
#pragma unroll
        for (int j = 0; j < 4; ++j)
#pragma unroll
            for (int e = 0; e < 4; ++e) o[i][j][e] = 0.0f;

#pragma unroll
    for (int ks = 0; ks < 2; ++ks) {
        bf16x8 ap[4], bvv[4];
#pragma unroll
        for (int t = 0; t < 4; ++t)
            ap[t] = *(const bf16x8*)(P + (t * 16 + l16) * 72 + ks * 32 + quad * 8);
#pragma unroll
        for (int t = 0; t < 4; ++t)
            bvv[t] = *(const bf16x8*)(VT + (t * 16 + l16) * 72 + ks * 32 + quad * 8);
#pragma unroll
        for (int mt = 0; mt < 4; ++mt)
#pragma unroll
            for (int nt = 0; nt < 4; ++nt)
                o[mt][nt] = __builtin_amdgcn_mfma_f32_16x16x32_bf16(
                    ap[mt], bvv[nt], o[mt][nt], 0, 0, 0);
    }
    __syncthreads();

    // write O into VT region as [tok][dj]
#pragma unroll
    for (int mt = 0; mt < 4; ++mt)
#pragma unroll
        for (int e = 0; e < 4; ++e) {
            int row = mt * 16 + quad * 4 + e;
#pragma unroll
            for (int nt = 0; nt < 4; ++nt)
                VT[row * 72 + nt * 16 + l16] = (__bf16)o[mt][nt][e];
        }
    __syncthreads();

    __bf16* yb = (shifted ? y2 : y1) + (size_t)b * HW * 384;
#pragma unroll
    for (int it = 0; it < 8; ++it) {
        int unit = it * 64 + l;
        int tok = unit >> 3, c8 = unit & 7;
        int hh = h0 + (tok >> 3), ww = w0 + (tok & 7);
        if ((unsigned)hh < 128u && (unsigned)ww < 128u)
            *(uint4*)(yb + (size_t)(hh * 128 + ww) * 384 + cbase + c8 * 8) =
                *(const uint4*)(VT + tok * 72 + c8 * 8);
    }
}

// ---------------------------------------------------------------------------
// K3: out[b][o][hw] (fp32) = w_head[o][c] * (y1+y2)[b][hw][c] + b_head[o]
// A = (y1+y2) (m=hw), B = w_head (n=o); both k-contiguous. float4 hw stores.
// ---------------------------------------------------------------------------
__global__ __launch_bounds__(256) void k_head(const __bf16* __restrict__ y1,
    const __bf16* __restrict__ y2, const float* __restrict__ wh,
    const float* __restrict__ bh, float* __restrict__ out)
{
    __shared__ __bf16 As[128 * 72];  // (y1+y2) tile [hw][c]
    __shared__ __bf16 Bs[128 * 72];  // w_head tile [o][c]
    const int tid = threadIdx.x;
    const int hw0 = blockIdx.x * 128;
    const int o0  = blockIdx.y * 128;
    const int b   = blockIdx.z;
    const __bf16* y1b = y1 + (size_t)b * HW * 384;
    const __bf16* y2b = y2 + (size_t)b * HW * 384;

    f32x4 acc[4][4];
#pragma unroll
    for (int i = 0; i < 4; ++i)
#pragma unroll
        for (int j = 0; j < 4; ++j)
#pragma unroll
            for (int e = 0; e < 4; ++e) acc[i][j][e] = 0.0f;

    const int l = tid & 63, wv = tid >> 6;
    const int wm = wv & 1;    // hw 64-half
    const int wn = wv >> 1;   // o 64-half
    const int l16 = l & 15, quad = l >> 4;

    for (int kt = 0; kt < 6; ++kt) {
        const int c0 = kt * 64;
        // stage y tile (fused y1+y2)
#pragma unroll
        for (int it = 0; it < 4; ++it) {
            int unit = it * 256 + tid;
            int hw = unit >> 3, c8 = unit & 7;
            size_t off = (size_t)(hw0 + hw) * 384 + c0 + c8 * 8;
            U4B8 t1, t2, r;
            t1.u = *(const uint4*)(y1b + off);
            t2.u = *(const uint4*)(y2b + off);
#pragma unroll
            for (int e = 0; e < 8; ++e)
                r.h[e] = (__bf16)((float)t1.h[e] + (float)t2.h[e]);
            *(uint4*)(As + hw * 72 + c8 * 8) = r.u;
        }
        // stage w_head tile
#pragma unroll
        for (int it = 0; it < 8; ++it) {
            int unit = it * 256 + tid;
            int o = unit >> 4, ch = unit & 15;
            float4 f = *(const float4*)(wh + (size_t)(o0 + o) * 384 + c0 + ch * 4);
            U2B4 t;
            t.h[0] = (__bf16)f.x; t.h[1] = (__bf16)f.y;
            t.h[2] = (__bf16)f.z; t.h[3] = (__bf16)f.w;
            *(uint2*)(Bs + o * 72 + ch * 4) = t.u;
        }
        __syncthreads();
#pragma unroll
        for (int ks = 0; ks < 2; ++ks) {
            bf16x8 a[4], bb[4];
#pragma unroll
            for (int t = 0; t < 4; ++t)
                a[t] = *(const bf16x8*)(As + (wm * 64 + t * 16 + l16) * 72 + ks * 32 + quad * 8);
#pragma unroll
            for (int t = 0; t < 4; ++t)
                bb[t] = *(const bf16x8*)(Bs + (wn * 64 + t * 16 + l16) * 72 + ks * 32 + quad * 8);
#pragma unroll
            for (int mt = 0; mt < 4; ++mt)
#pragma unroll
                for (int nt = 0; nt < 4; ++nt)
                    acc[mt][nt] = __builtin_amdgcn_mfma_f32_16x16x32_bf16(
                        a[mt], bb[nt], acc[mt][nt], 0, 0, 0);
        }
        __syncthreads();
    }

    // epilogue: D[m=hw][n=o]; col=l16 -> o, rows quad*4+e -> hw (float4 stores)
#pragma unroll
    for (int nt = 0; nt < 4; ++nt) {
        int oo = o0 + wn * 64 + nt * 16 + l16;
        float bb_ = bh[oo];
        float* ob = out + ((size_t)b * 384 + oo) * HW + hw0 + wm * 64;
#pragma unroll
        for (int mt = 0; mt < 4; ++mt) {
            float4 f;
            f.x = acc[mt][nt][0] + bb_;
            f.y = acc[mt][nt][1] + bb_;
            f.z = acc[mt][nt][2] + bb_;
            f.w = acc[mt][nt][3] + bb_;
            *(float4*)(ob + mt * 16 + quad * 4) = f;
        }
    }
}

extern "C" void kernel_launch(void* const* d_in, const int* in_sizes, int n_in,
                              void* d_out, int out_size, void* d_ws, size_t ws_size,
                              hipStream_t stream) {
    const float* x  = (const float*)d_in[0];
    const float* wq = (const float*)d_in[1];
    const float* bq = (const float*)d_in[2];
    const float* wh = (const float*)d_in[3];
    const float* bh = (const float*)d_in[4];
    float* out = (float*)d_out;

    __bf16* qkv = (__bf16*)d_ws;                       // 4*16384*1152 bf16 = 151 MB
    __bf16* y1  = qkv + (size_t)4 * HW * QKV_C;        // 4*16384*384  bf16 = 50 MB
    __bf16* y2  = y1 + (size_t)4 * HW * 384;           // 50 MB

    k_qkv<<<dim3(128, 9, 4), 256, 0, stream>>>(x, wq, bq, qkv);
    k_attn<<<dim3(4360), 192, 0, stream>>>(qkv, y1, y2);
    k_head<<<dim3(128, 3, 4), 256, 0, stream>>>(y1, y2, wh, bh, out);
}

// Round 2
// 495.567 us; speedup vs baseline: 1.2490x; 1.2490x over previous
//
#include <hip/hip_runtime.h>

typedef __bf16 bf16x8 __attribute__((ext_vector_type(8)));
typedef float f32x4 __attribute__((ext_vector_type(4)));

#define HW 16384
#define QKV_C 1152
#define SP 66   // k_attn LDS row stride: 33 dwords == 1 mod 32 -> conflict-free

union U4B8 { uint4 u; bf16x8 v; __bf16 h[8]; };
union U2B4 { uint2 u; __bf16 h[4]; };

// ---------------------------------------------------------------------------
// K1: qkv[b][hw][o] (bf16, token-major) = w_qkv[o][c] * x[b][c][hw] + b_qkv[o]
// grid (128 hw-tiles, 9 o-tiles, 4 b), 256 threads (4 waves, 2x2 wave grid)
// x-transpose staging: 8 scalar c-loads per lane -> one ds_write_b128
// (conflict-free; the old 4hw-x-1c scalar-write pattern was a 16-way conflict)
// ---------------------------------------------------------------------------
__global__ __launch_bounds__(256) void k_qkv(const float* __restrict__ x,
    const float* __restrict__ wq, const float* __restrict__ bq,
    __bf16* __restrict__ qkv)
{
    __shared__ __bf16 As[128 * 72];  // w_qkv tile [o][c]
    __shared__ __bf16 Bs[128 * 72];  // x tile [hw][c]
    const int tid = threadIdx.x;
    const int hw0 = blockIdx.x * 128;
    const int o0  = blockIdx.y * 128;
    const int b   = blockIdx.z;
    const float* xb = x + (size_t)b * 384 * HW;

    f32x4 acc[4][4];
#pragma unroll
    for (int i = 0; i < 4; ++i)
#pragma unroll
        for (int j = 0; j < 4; ++j)
#pragma unroll
            for (int e = 0; e < 4; ++e) acc[i][j][e] = 0.0f;

    const int l = tid & 63;
    const int wv = tid >> 6;
    const int wm = wv & 1;    // o 64-half
    const int wn = wv >> 1;   // hw 64-half
    const int l16 = l & 15, quad = l >> 4;

    for (int kt = 0; kt < 6; ++kt) {
        const int c0 = kt * 64;
        // stage w_qkv tile: 128 o x 64 c (fp32 -> bf16), uint2 writes (clean)
#pragma unroll
        for (int it = 0; it < 8; ++it) {
            int unit = it * 256 + tid;
            int o = unit >> 4, ch = unit & 15;
            float4 f = *(const float4*)(wq + (size_t)(o0 + o) * 384 + c0 + ch * 4);
            U2B4 t;
            t.h[0] = (__bf16)f.x; t.h[1] = (__bf16)f.y;
            t.h[2] = (__bf16)f.z; t.h[3] = (__bf16)f.w;
            *(uint2*)(As + o * 72 + ch * 4) = t.u;
        }
        // stage x tile transposed: lane gathers 8 consecutive c (scalar,
        // coalesced across lanes in hw), writes one b128 -> zero conflicts
#pragma unroll
        for (int ph = 0; ph < 4; ++ph) {
            int unit = ph * 256 + tid;
            int hw = unit & 127, c8 = unit >> 7;
            const float* xp = xb + (size_t)(c0 + c8 * 8) * HW + hw0 + hw;
            U4B8 t;
#pragma unroll
            for (int j = 0; j < 8; ++j) t.h[j] = (__bf16)xp[(size_t)j * HW];
            *(uint4*)(Bs + hw * 72 + c8 * 8) = t.u;
        }
        __syncthreads();
#pragma unroll
        for (int ks = 0; ks < 2; ++ks) {
            bf16x8 a[4], bb[4];
#pragma unroll
            for (int t = 0; t < 4; ++t)
                a[t] = *(const bf16x8*)(As + (wm * 64 + t * 16 + l16) * 72 + ks * 32 + quad * 8);
#pragma unroll
            for (int t = 0; t < 4; ++t)
                bb[t] = *(const bf16x8*)(Bs + (wn * 64 + t * 16 + l16) * 72 + ks * 32 + quad * 8);
#pragma unroll
            for (int mt = 0; mt < 4; ++mt)
#pragma unroll
                for (int nt = 0; nt < 4; ++nt)
                    acc[mt][nt] = __builtin_amdgcn_mfma_f32_16x16x32_bf16(
                        a[mt], bb[nt], acc[mt][nt], 0, 0, 0);
        }
        __syncthreads();
    }

    // epilogue: D[m=o][n=hw]; C-layout col=l16 -> hw, row=quad*4+e -> o
    __bf16* qb = qkv + (size_t)b * HW * QKV_C;
#pragma unroll
    for (int mt = 0; mt < 4; ++mt) {
        int oo = o0 + wm * 64 + mt * 16 + quad * 4;
        float4 bias = *(const float4*)(bq + oo);
#pragma unroll
        for (int nt = 0; nt < 4; ++nt) {
            int hw = hw0 + wn * 64 + nt * 16 + l16;
            U2B4 t;
            t.h[0] = (__bf16)(acc[mt][nt][0] + bias.x);
            t.h[1] = (__bf16)(acc[mt][nt][1] + bias.y);
            t.h[2] = (__bf16)(acc[mt][nt][2] + bias.z);
            t.h[3] = (__bf16)(acc[mt][nt][3] + bias.w);
            *(uint2*)(qb + (size_t)hw * QKV_C + oo) = t.u;
        }
    }
}

// ---------------------------------------------------------------------------
// K2: windowed MHA. One wave per (window, head, branch). 192 thr = 3 waves.
// LDS row stride SP=66 (33 dw == 1 mod 32): VT writes 8-way -> free,
// P/O writes 4-way -> free.
// ---------------------------------------------------------------------------
__global__ __launch_bounds__(192) void k_attn(const __bf16* __restrict__ qkv,
    __bf16* __restrict__ y1, __bf16* __restrict__ y2)
{
    __shared__ __bf16 sm[3][2][64 * SP];
    const int tid = threadIdx.x;
    const int l = tid & 63, wv = tid >> 6;
    const int wid = blockIdx.x * 3 + wv;
    const bool shifted = wid >= 6144;
    const int w2 = shifted ? wid - 6144 : wid;
    const int head = w2 % 6;
    const int win = w2 / 6;
    const int nw = shifted ? 17 : 16;
    const int wx = win % nw;
    const int t2 = win / nw;
    const int wy = t2 % nw;
    const int b  = t2 / nw;
    const int h0 = wy * 8 - (shifted ? 4 : 0);
    const int w0 = wx * 8 - (shifted ? 4 : 0);
    const __bf16* qb = qkv + (size_t)b * HW * QKV_C;
    __bf16* VT = &sm[wv][0][0];  // V^T [c][tok], later reused as O [tok][c]
    __bf16* P  = &sm[wv][1][0];  // P  [tok_q][tok_kv]
    const int l16 = l & 15, quad = l >> 4;
    const int cbase = head * 64;

    // stage V^T
#pragma unroll
    for (int it = 0; it < 8; ++it) {
        int unit = it * 64 + l;
        int tok = unit >> 3, c8 = unit & 7;
        int hh = h0 + (tok >> 3), ww = w0 + (tok & 7);
        U4B8 t;
        if ((unsigned)hh < 128u && (unsigned)ww < 128u)
            t.u = *(const uint4*)(qb + (size_t)(hh * 128 + ww) * QKV_C + 768 + cbase + c8 * 8);
        else
            t.u = make_uint4(0, 0, 0, 0);
#pragma unroll
        for (int e = 0; e < 8; ++e) VT[(c8 * 8 + e) * SP + tok] = t.h[e];
    }

    // per-16-token-tile offsets for this lane
    size_t toff[4]; bool tval[4];
#pragma unroll
    for (int t = 0; t < 4; ++t) {
        int tok = t * 16 + l16;
        int hh = h0 + (tok >> 3), ww = w0 + (tok & 7);
        tval[t] = ((unsigned)hh < 128u && (unsigned)ww < 128u);
        toff[t] = tval[t] ? (size_t)(hh * 128 + ww) * QKV_C : 0;
    }

    // S = Q K^T  (Q,K fragments direct from global; token-major layout matches)
    f32x4 s[4][4];
#pragma unroll
    for (int i = 0; i < 4; ++i)
#pragma unroll
        for (int j = 0; j < 4; ++j)
#pragma unroll
            for (int e = 0; e < 4; ++e) s[i][j][e] = 0.0f;

#pragma unroll
    for (int ks = 0; ks < 2; ++ks) {
        bf16x8 aq[4], bk[4];
#pragma unroll
        for (int t = 0; t < 4; ++t) {
            U4B8 uq, uk;
            if (tval[t]) {
                uq.u = *(const uint4*)(qb + toff[t] + cbase + ks * 32 + quad * 8);
                uk.u = *(const uint4*)(qb + toff[t] + 384 + cbase + ks * 32 + quad * 8);
            } else {
                uq.u = make_uint4(0, 0, 0, 0);
                uk.u = make_uint4(0, 0, 0, 0);
            }
            aq[t] = uq.v;
            bk[t] = uk.v;
        }
#pragma unroll
        for (int mt = 0; mt < 4; ++mt)
#pragma unroll
            for (int nt = 0; nt < 4; ++nt)
                s[mt][nt] = __builtin_amdgcn_mfma_f32_16x16x32_bf16(
                    aq[mt], bk[nt], s[mt][nt], 0, 0, 0);
    }

    // softmax (scale 1/8); row = mt*16 + quad*4 + e, cols across l16 x nt
#pragma unroll
    for (int mt = 0; mt < 4; ++mt) {
#pragma unroll
        for (int e = 0; e < 4; ++e) {
            float m_ = fmaxf(fmaxf(s[mt][0][e], s[mt][1][e]),
                             fmaxf(s[mt][2][e], s[mt][3][e]));
#pragma unroll
            for (int st = 1; st < 16; st <<= 1) m_ = fmaxf(m_, __shfl_xor(m_, st, 64));
            float p[4];
#pragma unroll
            for (int nt = 0; nt < 4; ++nt) p[nt] = __expf((s[mt][nt][e] - m_) * 0.125f);
            float sum = p[0] + p[1] + p[2] + p[3];
#pragma unroll
            for (int st = 1; st < 16; st <<= 1) sum += __shfl_xor(sum, st, 64);
            float r = __fdividef(1.0f, sum);
            int row = mt * 16 + quad * 4 + e;
#pragma unroll
            for (int nt = 0; nt < 4; ++nt)
                P[row * SP + nt * 16 + l16] = (__bf16)(p[nt] * r);
        }
    }
    __syncthreads();

    // O = P V
    f32x4 o[4][4];
#pragma unroll
    for (int i = 0; i < 4; ++i)
#pragma unroll
        for (int j = 0; j < 4; ++j)
#pragma unroll
            for (int e = 0; e < 4; ++e) o[i][j][e] = 0.0f;

#pragma unroll
    for (int ks = 0; ks < 2; ++ks) {
        bf16x8 ap[4], bvv[4];
#pragma unroll
        for (int t = 0; t < 4; ++t)
            ap[t] = *(const bf16x8*)(P + (t * 16 + l16) * SP + ks * 32 + quad * 8);
#pragma unroll
        for (int t = 0; t < 4; ++t)
            bvv[t] = *(const bf16x8*)(VT + (t * 16 + l16) * SP + ks * 32 + quad * 8);
#pragma unroll
        for (int mt = 0; mt < 4; ++mt)
#pragma unroll
            for (int nt = 0; nt < 4; ++nt)
                o[mt][nt] = __builtin_amdgcn_mfma_f32_16x16x32_bf16(
                    ap[mt], bvv[nt], o[mt][nt], 0, 0, 0);
    }
    __syncthreads();

    // write O into VT region as [tok][dj]
#pragma unroll
    for (int mt = 0; mt < 4; ++mt)
#pragma unroll
        for (int e = 0; e < 4; ++e) {
            int row = mt * 16 + quad * 4 + e;
#pragma unroll
            for (int nt = 0; nt < 4; ++nt)
                VT[row * SP + nt * 16 + l16] = (__bf16)o[mt][nt][e];
        }
    __syncthreads();

    __bf16* yb = (shifted ? y2 : y1) + (size_t)b * HW * 384;
#pragma unroll
    for (int it = 0; it < 8; ++it) {
        int unit = it * 64 + l;
        int tok = unit >> 3, c8 = unit & 7;
        int hh = h0 + (tok >> 3), ww = w0 + (tok & 7);
        if ((unsigned)hh < 128u && (unsigned)ww < 128u)
            *(uint4*)(yb + (size_t)(hh * 128 + ww) * 384 + cbase + c8 * 8) =
                *(const uint4*)(VT + tok * SP + c8 * 8);
    }
}

// ---------------------------------------------------------------------------
// K3: out[b][o][hw] (fp32) = w_head[o][c] * (y1+y2)[b][hw][c] + b_head[o]
// A = (y1+y2) (m=hw), B = w_head (n=o); both k-contiguous. float4 hw stores.
// ---------------------------------------------------------------------------
__global__ __launch_bounds__(256) void k_head(const __bf16* __restrict__ y1,
    const __bf16* __restrict__ y2, const float* __restrict__ wh,
    const float* __restrict__ bh, float* __restrict__ out)
{
    __shared__ __bf16 As[128 * 72];  // (y1+y2) tile [hw][c]
    __shared__ __bf16 Bs[128 * 72];  // w_head tile [o][c]
    const int tid = threadIdx.x;
    const int hw0 = blockIdx.x * 128;
    const int o0  = blockIdx.y * 128;
    const int b   = blockIdx.z;
    const __bf16* y1b = y1 + (size_t)b * HW * 384;
    const __bf16* y2b = y2 + (size_t)b * HW * 384;

    f32x4 acc[4][4];
#pragma unroll
    for (int i = 0; i < 4; ++i)
#pragma unroll
        for (int j = 0; j < 4; ++j)
#pragma unroll
            for (int e = 0; e < 4; ++e) acc[i][j][e] = 0.0f;

    const int l = tid & 63, wv = tid >> 6;
    const int wm = wv & 1;    // hw 64-half
    const int wn = wv >> 1;   // o 64-half
    const int l16 = l & 15, quad = l >> 4;

    for (int kt = 0; kt < 6; ++kt) {
        const int c0 = kt * 64;
        // stage y tile (fused y1+y2)
#pragma unroll
        for (int it = 0; it < 4; ++it) {
            int unit = it * 256 + tid;
            int hw = unit >> 3, c8 = unit & 7;
            size_t off = (size_t)(hw0 + hw) * 384 + c0 + c8 * 8;
            U4B8 t1, t2, r;
            t1.u = *(const uint4*)(y1b + off);
            t2.u = *(const uint4*)(y2b + off);
#pragma unroll
            for (int e = 0; e < 8; ++e)
                r.h[e] = (__bf16)((float)t1.h[e] + (float)t2.h[e]);
            *(uint4*)(As + hw * 72 + c8 * 8) = r.u;
        }
        // stage w_head tile
#pragma unroll
        for (int it = 0; it < 8; ++it) {
            int unit = it * 256 + tid;
            int o = unit >> 4, ch = unit & 15;
            float4 f = *(const float4*)(wh + (size_t)(o0 + o) * 384 + c0 + ch * 4);
            U2B4 t;
            t.h[0] = (__bf16)f.x; t.h[1] = (__bf16)f.y;
            t.h[2] = (__bf16)f.z; t.h[3] = (__bf16)f.w;
            *(uint2*)(Bs + o * 72 + ch * 4) = t.u;
        }
        __syncthreads();
#pragma unroll
        for (int ks = 0; ks < 2; ++ks) {
            bf16x8 a[4], bb[4];
#pragma unroll
            for (int t = 0; t < 4; ++t)
                a[t] = *(const bf16x8*)(As + (wm * 64 + t * 16 + l16) * 72 + ks * 32 + quad * 8);
#pragma unroll
            for (int t = 0; t < 4; ++t)
                bb[t] = *(const bf16x8*)(Bs + (wn * 64 + t * 16 + l16) * 72 + ks * 32 + quad * 8);
#pragma unroll
            for (int mt = 0; mt < 4; ++mt)
#pragma unroll
                for (int nt = 0; nt < 4; ++nt)
                    acc[mt][nt] = __builtin_amdgcn_mfma_f32_16x16x32_bf16(
                        a[mt], bb[nt], acc[mt][nt], 0, 0, 0);
        }
        __syncthreads();
    }

    // epilogue: D[m=hw][n=o]; col=l16 -> o, rows quad*4+e -> hw (float4 stores)
#pragma unroll
    for (int nt = 0; nt < 4; ++nt) {
        int oo = o0 + wn * 64 + nt * 16 + l16;
        float bb_ = bh[oo];
        float* ob = out + ((size_t)b * 384 + oo) * HW + hw0 + wm * 64;
#pragma unroll
        for (int mt = 0; mt < 4; ++mt) {
            float4 f;
            f.x = acc[mt][nt][0] + bb_;
            f.y = acc[mt][nt][1] + bb_;
            f.z = acc[mt][nt][2] + bb_;
            f.w = acc[mt][nt][3] + bb_;
            *(float4*)(ob + mt * 16 + quad * 4) = f;
        }
    }
}

extern "C" void kernel_launch(void* const* d_in, const int* in_sizes, int n_in,
                              void* d_out, int out_size, void* d_ws, size_t ws_size,
                              hipStream_t stream) {
    const float* x  = (const float*)d_in[0];
    const float* wq = (const float*)d_in[1];
    const float* bq = (const float*)d_in[2];
    const float* wh = (const float*)d_in[3];
    const float* bh = (const float*)d_in[4];
    float* out = (float*)d_out;

    __bf16* qkv = (__bf16*)d_ws;                       // 4*16384*1152 bf16 = 151 MB
    __bf16* y1  = qkv + (size_t)4 * HW * QKV_C;        // 4*16384*384  bf16 = 50 MB
    __bf16* y2  = y1 + (size_t)4 * HW * 384;           // 50 MB

    k_qkv<<<dim3(128, 9, 4), 256, 0, stream>>>(x, wq, bq, qkv);
    k_attn<<<dim3(4360), 192, 0, stream>>>(qkv, y1, y2);
    k_head<<<dim3(128, 3, 4), 256, 0, stream>>>(y1, y2, wh, bh, out);
}